// Round 2
// baseline (256.383 us; speedup 1.0000x reference)
//
#include <hip/hip_runtime.h>
#include <hip/hip_bf16.h>

// ECE over logits (8,19,512,1024) f32, labels (8,512,1024) int32.
// confidence = 1/sum(exp(l - lmax)); prediction = argmax (first-max, matches jnp).
// bin = clip(ceil(conf*15)-1, 0, 14)  ==  searchsorted(linspace(0,1,16), conf, left)-1 clipped.
// Single fused kernel: per-pixel -> LDS-replicated bins -> global atomics;
// last block to finish computes the final scalar (device-scope done counter).
// Logits/labels streamed with non-temporal loads (read-once data, skip cache alloc).

constexpr int NBINS = 15;
constexpr int NC    = 19;      // classes (fixed by reference)
constexpr int REP   = 8;       // LDS bin replicas to cut same-address atomic contention
constexpr int HWSH  = 19;      // H*W = 512*1024 = 2^19 (fixed by reference)

typedef float f32x4 __attribute__((ext_vector_type(4)));
typedef int   i32x4 __attribute__((ext_vector_type(4)));

__global__ __launch_bounds__(256) void ece_fused_kernel(
    const float* __restrict__ logits,
    const int*   __restrict__ labels,
    double*       __restrict__ g_conf,   // [NBINS]
    unsigned int* __restrict__ g_cnt,    // [NBINS]
    unsigned int* __restrict__ g_corr,   // [NBINS]
    unsigned int* __restrict__ g_done,   // [1]
    float*        __restrict__ out,
    int P4)                              // number of 4-pixel groups
{
    __shared__ float    s_conf[NBINS][REP];
    __shared__ unsigned s_cnt [NBINS][REP];
    __shared__ unsigned s_corr[NBINS][REP];
    __shared__ unsigned s_last;

    const int t = threadIdx.x;
    for (int i = t; i < NBINS * REP; i += 256) {
        (&s_conf[0][0])[i] = 0.0f;
        (&s_cnt [0][0])[i] = 0u;
        (&s_corr[0][0])[i] = 0u;
    }
    if (t == 0) s_last = 0;
    __syncthreads();

    const int rep    = t & (REP - 1);
    const int HW     = 1 << HWSH;
    const int stride = gridDim.x * 256;

    #pragma unroll 1
    for (int g = blockIdx.x * 256 + t; g < P4; g += stride) {
        const int p   = g << 2;              // first pixel of this 4-group
        const int n   = p >> HWSH;           // image index
        const int rem = p & (HW - 1);        // h*W + w within the image
        const float* base = logits + (((size_t)(n * NC)) << HWSH) + rem;

        // All 19 class values for 4 consecutive pixels; NT: read-once stream.
        float v[NC][4];
        #pragma unroll
        for (int c = 0; c < NC; ++c) {
            const f32x4 x = __builtin_nontemporal_load(
                reinterpret_cast<const f32x4*>(base + ((size_t)c << HWSH)));
            v[c][0] = x[0]; v[c][1] = x[1]; v[c][2] = x[2]; v[c][3] = x[3];
        }
        const i32x4 lab = __builtin_nontemporal_load(
            reinterpret_cast<const i32x4*>(labels + p));
        const int labv[4] = { lab[0], lab[1], lab[2], lab[3] };

        #pragma unroll
        for (int j = 0; j < 4; ++j) {
            float mx = v[0][j];
            int   am = 0;
            #pragma unroll
            for (int c = 1; c < NC; ++c) {
                if (v[c][j] > mx) { mx = v[c][j]; am = c; }  // strict > = first max (jnp.argmax)
            }
            float s = 0.0f;
            #pragma unroll
            for (int c = 0; c < NC; ++c) s += __expf(v[c][j] - mx);
            const float conf = 1.0f / s;

            int b = (int)ceilf(conf * 15.0f) - 1;
            b = b < 0 ? 0 : (b > NBINS - 1 ? NBINS - 1 : b);

            atomicAdd(&s_cnt [b][rep], 1u);
            atomicAdd(&s_conf[b][rep], conf);
            if (am == labv[j]) atomicAdd(&s_corr[b][rep], 1u);
        }
    }
    __syncthreads();

    // Block reduction -> device-scope global atomics.
    if (t < NBINS) {
        unsigned cnt = 0u, cor = 0u;
        float cf = 0.0f;
        #pragma unroll
        for (int r = 0; r < REP; ++r) {
            cnt += s_cnt [t][r];
            cor += s_corr[t][r];
            cf  += s_conf[t][r];
        }
        if (cnt) {
            atomicAdd(&g_cnt [t], cnt);
            atomicAdd(&g_corr[t], cor);
            atomicAdd(&g_conf[t], (double)cf);
        }
    }
    __syncthreads();   // all lanes' global atomics issued & drained before done-count

    if (t == 0) {
        __threadfence();  // release: this block's sums visible device-wide
        const unsigned prev = __hip_atomic_fetch_add(
            g_done, 1u, __ATOMIC_ACQ_REL, __HIP_MEMORY_SCOPE_AGENT);
        if (prev == gridDim.x - 1) s_last = 1;
    }
    __syncthreads();

    if (s_last && t == 0) {
        const double total = (double)P4 * 4.0;
        double e = 0.0;
        for (int b = 0; b < NBINS; ++b) {
            const unsigned cnt = __hip_atomic_load(&g_cnt[b],  __ATOMIC_RELAXED, __HIP_MEMORY_SCOPE_AGENT);
            const unsigned cor = __hip_atomic_load(&g_corr[b], __ATOMIC_RELAXED, __HIP_MEMORY_SCOPE_AGENT);
            const double   cf  = __hip_atomic_load(&g_conf[b], __ATOMIC_RELAXED, __HIP_MEMORY_SCOPE_AGENT);
            if (cnt) {
                const double c = (double)cnt;
                e += fabs(cf / c - (double)cor / c) * (c / total);
            }
        }
        out[0] = (float)e;
    }
}

extern "C" void kernel_launch(void* const* d_in, const int* in_sizes, int n_in,
                              void* d_out, int out_size, void* d_ws, size_t ws_size,
                              hipStream_t stream) {
    const float* logits = (const float*)d_in[0];
    const int*   labels = (const int*)d_in[1];   // harness converts integer inputs to int32
    float*       out    = (float*)d_out;

    const int P  = in_sizes[1];   // 8*512*1024 = 4,194,304 pixels
    const int P4 = P >> 2;

    // Workspace: [0..120) double conf[15]; [128..188) uint cnt[15];
    //            [192..252) uint corr[15]; [252..256) uint done
    double*       g_conf = (double*)d_ws;
    unsigned int* g_cnt  = (unsigned int*)((char*)d_ws + 128);
    unsigned int* g_corr = (unsigned int*)((char*)d_ws + 192);
    unsigned int* g_done = (unsigned int*)((char*)d_ws + 252);

    hipMemsetAsync(d_ws, 0, 256, stream);  // deterministic re-zero every call

    int blocks = (P4 + 255) / 256;
    if (blocks > 2048) blocks = 2048;
    ece_fused_kernel<<<blocks, 256, 0, stream>>>(
        logits, labels, g_conf, g_cnt, g_corr, g_done, out, P4);
}